// Round 8
// baseline (372.607 us; speedup 1.0000x reference)
//
#include <hip/hip_runtime.h>
#include <hip/hip_bf16.h>
#include <stdint.h>

// Shapes (fixed): B=4, N=8, Q=256, K=1024, D_MODEL=512, H=8, Dh=64, R=8, sigma=0.05

typedef __attribute__((ext_vector_type(8))) short bf16x8;
typedef __attribute__((ext_vector_type(4))) float f32x4;
typedef __attribute__((ext_vector_type(2))) float f32x2;

__device__ __forceinline__ unsigned short f2b(float f){
    unsigned int u = __builtin_bit_cast(unsigned int, f);
    unsigned int r = u + 0x7fffu + ((u >> 16) & 1u);   // RNE
    return (unsigned short)(r >> 16);
}

// packed f32->bf16x2 (RNE), single HW instr
__device__ __forceinline__ unsigned cvtpk2(float lo, float hi){
    unsigned r;
    asm("v_cvt_pk_bf16_f32 %0, %1, %2" : "=v"(r) : "v"(lo), "v"(hi));
    return r;
}

// single-level XOR swizzle for 64-col bf16 LDS tiles (0 conflicts measured r2)
__device__ __forceinline__ int swz(int row, int byteInRow){
    return row*128 + (byteInRow ^ ((row & 7) << 4));
}

// direct-to-LDS async copy, 16B per lane; LDS dest is wave-uniform base + lane*16
#define GLDS16(g, l) __builtin_amdgcn_global_load_lds( \
    (const __attribute__((address_space(1))) void*)(g), \
    (__attribute__((address_space(3))) void*)(l), 16, 0, 0)

// DPP butterflies within 16-lane row
template<int CTRL>
__device__ __forceinline__ float dpp_mov(float x){
    return __builtin_bit_cast(float,
        __builtin_amdgcn_update_dpp(0, __builtin_bit_cast(int, x), CTRL, 0xF, 0xF, true));
}
__device__ __forceinline__ float grp16_max(float x){
    x = fmaxf(x, dpp_mov<0xB1>(x));
    x = fmaxf(x, dpp_mov<0x4E>(x));
    x = fmaxf(x, dpp_mov<0x141>(x));
    x = fmaxf(x, dpp_mov<0x140>(x));
    return x;
}
__device__ __forceinline__ float grp16_sum(float x){
    x += dpp_mov<0xB1>(x);
    x += dpp_mov<0x4E>(x);
    x += dpp_mov<0x141>(x);
    x += dpp_mov<0x140>(x);
    return x;
}

// ---------------- all 4 weight transposes in one launch ---------------------
__global__ __launch_bounds__(256) void wt4_kernel(
    const float* __restrict__ Wq, const float* __restrict__ Wk,
    const float* __restrict__ Wv, const float* __restrict__ Wo,
    unsigned short* __restrict__ WtBase){
    __shared__ float tile[64][65];
    int kt = blockIdx.x, nt = blockIdx.y, wsel = blockIdx.z;
    const float* W = (wsel == 0) ? Wq : (wsel == 1) ? Wk : (wsel == 2) ? Wv : Wo;
    unsigned short* Wt = WtBase + (size_t)wsel * 262144;
    int tid = threadIdx.x;
    #pragma unroll
    for(int it=0; it<16; ++it){
        int idx = it*256 + tid;
        int r = idx >> 6, c = idx & 63;
        tile[r][c] = W[(kt*64 + r)*512 + nt*64 + c];
    }
    __syncthreads();
    #pragma unroll
    for(int it=0; it<16; ++it){
        int idx = it*256 + tid;
        int r = idx >> 6, c = idx & 63;
        Wt[(nt*64 + r)*512 + kt*64 + c] = f2b(tile[c][r]);
    }
}

// ---------------- positional features (rank-3 collapsed bias) ---------------
__global__ __launch_bounds__(256) void posfeat_kernel(
    const float* __restrict__ qpos, const float* __restrict__ kpos,
    const float* __restrict__ Wqb,  const float* __restrict__ Wkb,
    const int* __restrict__ mask,
    float* __restrict__ qwg,        // [1024][4]
    float* __restrict__ kfg){       // [4096][4]
    const float L2E = 1.4426950408889634f;
    const float S8  = 0.35355339059327373f;
    int id = blockIdx.x*256 + threadIdx.x;
    if(id < 1024){
        const float* p = qpos + id*3;
        float x = p[0], y = p[1], z = p[2];
        float qw0 = 400.f*x, qw1 = 400.f*y, qw2 = 400.f*z;
        #pragma unroll
        for(int r=0;r<8;++r){
            float qb = x*Wqb[r] + y*Wqb[8+r] + z*Wqb[16+r];
            float c  = S8*qb;
            qw0 += c*Wkb[r];
            qw1 += c*Wkb[8+r];
            qw2 += c*Wkb[16+r];
        }
        float4 o = {L2E*qw0, L2E*qw1, L2E*qw2, 0.f};
        *reinterpret_cast<float4*>(qwg + (size_t)id*4) = o;
    } else if(id < 5120){
        int k = id - 1024;
        const float* p = kpos + k*3;
        float x = p[0], y = p[1], z = p[2];
        float n2 = -200.0f*(x*x + y*y + z*z)*L2E;
        int mk = mask[k];
        float4 o = {x, y, z, mk ? n2 : -3.0e38f};
        *reinterpret_cast<float4*>(kfg + (size_t)k*4) = o;
    }
}

// ---------------- f32 -> bf16 streaming convert (8 elems/thread) ------------
__global__ __launch_bounds__(256) void cvt_kernel(
    const float* __restrict__ in, unsigned short* __restrict__ out, int n8){
    for(int id = blockIdx.x*256 + threadIdx.x; id < n8; id += gridDim.x*256){
        const float4* ip = reinterpret_cast<const float4*>(in) + (size_t)id*2;
        float4 a = ip[0], b = ip[1];
        uint4 w;
        w.x = cvtpk2(a.x, a.y); w.y = cvtpk2(a.z, a.w);
        w.z = cvtpk2(b.x, b.y); w.w = cvtpk2(b.z, b.w);
        reinterpret_cast<uint4*>(out)[id] = w;
    }
}

// ---------------- GEMM (m97 structure): A bf16 [M][512] @ Bt bf16 -----------
template<int EPI>
__global__ __launch_bounds__(256, 4) void gemm512g(
    const unsigned short* __restrict__ A,
    const unsigned short* __restrict__ Bt,
    const float* __restrict__ bias,
    void* __restrict__ Cv){
    __shared__ alignas(16) char sm[32768];
    char* As = sm;
    char* Bs = sm + 16384;

    int nwg = gridDim.x;                     // divisible by 8
    int q8  = nwg >> 3;
    int bid = blockIdx.x;
    int wgid = (bid & 7)*q8 + (bid >> 3);    // XCD-chunked bijection
    int n0 = (wgid & 3)*128, m0 = (wgid >> 2)*128;

    int tid = threadIdx.x;
    int l = tid & 63, wid = tid >> 6;
    int wr = wid >> 1, wc = wid & 1;
    int l15 = l & 15, lg = l >> 4;

    int srow8 = l >> 3;
    int scolb = ((l & 7) ^ srow8) << 4;

    f32x4 acc[4][4];
    const f32x4 z4 = {0.f,0.f,0.f,0.f};
    #pragma unroll
    for(int m=0;m<4;++m)
        #pragma unroll
        for(int n=0;n<4;++n) acc[m][n] = z4;

    for(int kt=0; kt<8; ++kt){
        int k0 = kt*64;
        __syncthreads();
        #pragma unroll
        for(int i=0;i<4;++i){
            int row = wid*32 + i*8 + srow8;
            const char* asrc = (const char*)(A  + (size_t)(m0+row)*512 + k0) + scolb;
            const char* bsrc = (const char*)(Bt + (size_t)(n0+row)*512 + k0) + scolb;
            GLDS16(asrc, As + wid*4096 + i*1024);
            GLDS16(bsrc, Bs + wid*4096 + i*1024);
        }
        __syncthreads();
        #pragma unroll
        for(int kk=0; kk<2; ++kk){
            bf16x8 af[4], bfr[4];
            #pragma unroll
            for(int m=0;m<4;++m)
                af[m] = *reinterpret_cast<const bf16x8*>(As + swz(wr*64 + m*16 + l15, kk*64 + lg*16));
            #pragma unroll
            for(int n=0;n<4;++n)
                bfr[n] = *reinterpret_cast<const bf16x8*>(Bs + swz(wc*64 + n*16 + l15, kk*64 + lg*16));
            #pragma unroll
            for(int m=0;m<4;++m)
                #pragma unroll
                for(int n=0;n<4;++n)
                    acc[m][n] = __builtin_amdgcn_mfma_f32_16x16x32_bf16(af[m], bfr[n], acc[m][n], 0, 0, 0);
        }
    }

    if(EPI == 2){
        unsigned short* vpT = (unsigned short*)Cv;
        int z = m0 >> 10;
        #pragma unroll
        for(int m=0;m<4;++m){
            int kloc = (m0 & 1023) + wr*64 + m*16 + lg*4;
            #pragma unroll
            for(int n=0;n<4;++n){
                int col = n0 + wc*64 + n*16 + l15;   // h*64+d
                float bv = bias[col];
                int vrow = (z*8 + (col >> 6))*64 + (col & 63);
                uint2 w;
                w.x = cvtpk2(acc[m][n][0] + bv, acc[m][n][1] + bv);
                w.y = cvtpk2(acc[m][n][2] + bv, acc[m][n][3] + bv);
                *reinterpret_cast<uint2*>(vpT + (size_t)vrow*1024 + kloc) = w;
            }
        }
    } else {
        #pragma unroll
        for(int m=0;m<4;++m){
            int row = m0 + wr*64 + m*16 + lg*4;
            #pragma unroll
            for(int n=0;n<4;++n){
                int col = n0 + wc*64 + n*16 + l15;
                float bv = bias[col];
                #pragma unroll
                for(int j=0;j<4;++j){
                    float val = acc[m][n][j] + bv;
                    if(EPI == 0)
                        reinterpret_cast<unsigned short*>(Cv)[(size_t)(row+j)*512 + col] = f2b(val);
                    else
                        reinterpret_cast<float*>(Cv)[(size_t)(row+j)*512 + col] = val;
                }
            }
        }
    }
}

// ---------------- attention v6: split-K flash, barrier-free inner loop ------
// 1024 blocks x 256 threads. Block = (z, h, q-quad of 64 rows).
// Wave = 32 q-rows (qg = wid&1) x 8 k-tiles (kh = wid>>1).
// attn4's inner loop verbatim; one LDS combine merges the two k-halves.
__global__ __launch_bounds__(256, 3) void attn6_kernel(
    const unsigned short* __restrict__ qp,   // [8192][512] bf16
    const unsigned short* __restrict__ kp,   // [32768][512] bf16
    const unsigned short* __restrict__ vpT,  // [(z*8+h)*64+d][1024] bf16
    const float* __restrict__ qwg,           // [1024][4] L2E-folded
    const float* __restrict__ kfg,           // [4096][4] L2E-folded
    unsigned short* __restrict__ ctxb){      // [8192][512] bf16
    __shared__ alignas(16) char sm[40960];   // 16KB Ps (4x4KB) + 24KB combine

    const float SCALE2 = 0.18033688011112042f;   // 0.125 * log2(e)
    const float THR = 10.0f;

    // decode: all 4 q-quads of one (z,h) on the same XCD
    int bid = blockIdx.x;
    int xcd = bid & 7, idx = bid >> 3;       // idx 0..127
    int zh = xcd*32 + (idx >> 2), qq = idx & 3;
    int z = zh >> 3, h = zh & 7;
    int b = z >> 3;
    int tid = threadIdx.x, l = tid & 63, wid = tid >> 6;
    int qg = wid & 1, kh = wid >> 1;
    int l15 = l & 15, lg = l >> 4;

    const unsigned short* kbase = kp  + (size_t)(z*1024)*512 + h*64;
    const unsigned short* vbase = vpT + (size_t)((z*8+h)*64)*1024;
    const float* kfb = kfg + (size_t)(b*1024)*4;
    char* Pw = sm + wid*4096;
    int qbase = z*256 + qq*64 + qg*32;

    // Q fragments: 2 q-subtiles x 2 d-halves (held for all tiles)
    bf16x8 qf[2][2];
    #pragma unroll
    for(int qh=0;qh<2;++qh)
        #pragma unroll
        for(int kk=0;kk<2;++kk)
            qf[qh][kk] = *reinterpret_cast<const bf16x8*>(
                qp + (size_t)(qbase + qh*16 + l15)*512 + h*64 + kk*32 + lg*8);

    f32x2 qwp[2][2][3];
    #pragma unroll
    for(int qh=0;qh<2;++qh){
        f32x4 qv[4];
        #pragma unroll
        for(int j=0;j<4;++j)
            qv[j] = *reinterpret_cast<const f32x4*>(
                qwg + (size_t)(b*256 + qq*64 + qg*32 + qh*16 + lg*4 + j)*4);
        #pragma unroll
        for(int p=0;p<2;++p)
            #pragma unroll
            for(int f=0;f<3;++f)
                qwp[qh][p][f] = (f32x2){qv[2*p][f], qv[2*p+1][f]};
    }

    float mrun[2][4];
    f32x4 psum[2];
    f32x4 acc[2][4];
    const f32x4 z4 = {0.f,0.f,0.f,0.f};
    #pragma unroll
    for(int qh=0;qh<2;++qh){
        #pragma unroll
        for(int j=0;j<4;++j) mrun[qh][j] = -3.0e38f;
        psum[qh] = z4;
        #pragma unroll
        for(int t=0;t<4;++t) acc[qh][t] = z4;
    }

    for(int kt=kh*8; kt<kh*8+8; ++kt){
        const unsigned short* ktk = kbase + (size_t)(kt*64)*512;
        bf16x8 kf[4][2];
        #pragma unroll
        for(int t=0;t<4;++t)
            #pragma unroll
            for(int kk=0;kk<2;++kk)
                kf[t][kk] = *reinterpret_cast<const bf16x8*>(
                    ktk + (size_t)(t*16 + l15)*512 + kk*32 + lg*8);
        f32x4 kv[4];
        #pragma unroll
        for(int t=0;t<4;++t)
            kv[t] = *reinterpret_cast<const f32x4*>(kfb + (size_t)(kt*64 + t*16 + l15)*4);

        f32x4 s[2][4];
        #pragma unroll
        for(int qh=0;qh<2;++qh)
            #pragma unroll
            for(int t=0;t<4;++t) s[qh][t] = z4;
        __builtin_amdgcn_s_setprio(1);
        #pragma unroll
        for(int t=0;t<4;++t)
            #pragma unroll
            for(int kk=0;kk<2;++kk)
                #pragma unroll
                for(int qh=0;qh<2;++qh)
                    s[qh][t] = __builtin_amdgcn_mfma_f32_16x16x32_bf16(qf[qh][kk], kf[t][kk], s[qh][t], 0, 0, 0);
        __builtin_amdgcn_s_setprio(0);

        // V fragments issued early so their latency hides under softmax VALU
        bf16x8 vf[4][2];
        #pragma unroll
        for(int t=0;t<4;++t)
            #pragma unroll
            for(int kk=0;kk<2;++kk)
                vf[t][kk] = *reinterpret_cast<const bf16x8*>(
                    vbase + (size_t)(t*16 + l15)*1024 + kt*64 + kk*32 + lg*8);

        #pragma unroll
        for(int t=0;t<4;++t){
            f32x2 c0 = {kv[t][0],kv[t][0]}, c1 = {kv[t][1],kv[t][1]},
                  c2 = {kv[t][2],kv[t][2]}, c3 = {kv[t][3],kv[t][3]};
            #pragma unroll
            for(int qh=0;qh<2;++qh){
                f32x2 b01 = qwp[qh][0][0]*c0 + qwp[qh][0][1]*c1 + qwp[qh][0][2]*c2 + c3;
                f32x2 b23 = qwp[qh][1][0]*c0 + qwp[qh][1][1]*c1 + qwp[qh][1][2]*c2 + c3;
                f32x2 s01 = {s[qh][t][0], s[qh][t][1]};
                f32x2 s23 = {s[qh][t][2], s[qh][t][3]};
                s01 = s01*SCALE2 + b01;
                s23 = s23*SCALE2 + b23;
                s[qh][t][0] = s01.x; s[qh][t][1] = s01.y;
                s[qh][t][2] = s23.x; s[qh][t][3] = s23.y;
            }
        }
        float pm[2][4];
        bool need = false;
        #pragma unroll
        for(int qh=0;qh<2;++qh)
            #pragma unroll
            for(int j=0;j<4;++j){
                float mx = fmaxf(fmaxf(s[qh][0][j], s[qh][1][j]), fmaxf(s[qh][2][j], s[qh][3][j]));
                mx = grp16_max(mx);
                pm[qh][j] = mx;
                need = need || (mx > mrun[qh][j] + THR);
            }
        if(__any(need ? 1 : 0)){
            #pragma unroll
            for(int qh=0;qh<2;++qh)
                #pragma unroll
                for(int j=0;j<4;++j){
                    float mn = fmaxf(mrun[qh][j], pm[qh][j]);
                    float scl = exp2f(mrun[qh][j] - mn);
                    mrun[qh][j] = mn;
                    psum[qh][j] *= scl;
                    #pragma unroll
                    for(int t=0;t<4;++t) acc[qh][t][j] *= scl;
                }
        }
        #pragma unroll
        for(int qh=0;qh<2;++qh){
            int row0 = qh*16 + lg*4;
            #pragma unroll
            for(int t=0;t<4;++t){
                float p0 = exp2f(s[qh][t][0] - mrun[qh][0]);
                float p1 = exp2f(s[qh][t][1] - mrun[qh][1]);
                float p2 = exp2f(s[qh][t][2] - mrun[qh][2]);
                float p3 = exp2f(s[qh][t][3] - mrun[qh][3]);
                psum[qh] += (f32x4){p0, p1, p2, p3};
                unsigned w01 = cvtpk2(p0, p1);
                unsigned w23 = cvtpk2(p2, p3);
                int cb = (t*16 + l15)*2;
                *reinterpret_cast<unsigned short*>(Pw + swz(row0+0, cb)) = (unsigned short)w01;
                *reinterpret_cast<unsigned short*>(Pw + swz(row0+1, cb)) = (unsigned short)(w01 >> 16);
                *reinterpret_cast<unsigned short*>(Pw + swz(row0+2, cb)) = (unsigned short)w23;
                *reinterpret_cast<unsigned short*>(Pw + swz(row0+3, cb)) = (unsigned short)(w23 >> 16);
            }
        }
        __builtin_amdgcn_s_setprio(1);
        #pragma unroll
        for(int kk=0;kk<2;++kk){
            #pragma unroll
            for(int qh=0;qh<2;++qh){
                bf16x8 pa = *reinterpret_cast<const bf16x8*>(Pw + swz(qh*16 + l15, kk*64 + lg*16));
                #pragma unroll
                for(int t=0;t<4;++t)
                    acc[qh][t] = __builtin_amdgcn_mfma_f32_16x16x32_bf16(pa, vf[t][kk], acc[qh][t], 0, 0, 0);
            }
        }
        __builtin_amdgcn_s_setprio(0);
    }

    // ---- split-K combine: kh=1 writes state, kh=0 merges + writes output ----
    char* cbuf = sm + 16384;
    if(kh == 1){
        uint4* cb = reinterpret_cast<uint4*>(cbuf + qg*12288 + l*192);
        #pragma unroll
        for(int qh=0;qh<2;++qh)
            #pragma unroll
            for(int t=0;t<4;++t)
                cb[qh*4+t] = __builtin_bit_cast(uint4, acc[qh][t]);
        cb[8] = __builtin_bit_cast(uint4, psum[0]);
        cb[9] = __builtin_bit_cast(uint4, psum[1]);
        f32x4 m0 = {mrun[0][0], mrun[0][1], mrun[0][2], mrun[0][3]};
        f32x4 m1 = {mrun[1][0], mrun[1][1], mrun[1][2], mrun[1][3]};
        cb[10] = __builtin_bit_cast(uint4, m0);
        cb[11] = __builtin_bit_cast(uint4, m1);
    }
    __syncthreads();
    if(kh == 1) return;

    const uint4* cb = reinterpret_cast<const uint4*>(cbuf + qg*12288 + l*192);
    f32x4 a1[2][4], ps1[2], mr1[2];
    #pragma unroll
    for(int qh=0;qh<2;++qh)
        #pragma unroll
        for(int t=0;t<4;++t)
            a1[qh][t] = __builtin_bit_cast(f32x4, cb[qh*4+t]);
    ps1[0] = __builtin_bit_cast(f32x4, cb[8]);
    ps1[1] = __builtin_bit_cast(f32x4, cb[9]);
    mr1[0] = __builtin_bit_cast(f32x4, cb[10]);
    mr1[1] = __builtin_bit_cast(f32x4, cb[11]);

    #pragma unroll
    for(int qh=0;qh<2;++qh){
        float rl[4];
        #pragma unroll
        for(int j=0;j<4;++j){
            float m0 = mrun[qh][j], m1 = mr1[qh][j];
            float mn = fmaxf(m0, m1);
            float s0 = exp2f(m0 - mn), s1 = exp2f(m1 - mn);
            float ps = psum[qh][j]*s0 + ps1[qh][j]*s1;
            rl[j] = 1.0f / grp16_sum(ps);
            #pragma unroll
            for(int t=0;t<4;++t)
                acc[qh][t][j] = acc[qh][t][j]*s0 + a1[qh][t][j]*s1;
        }
        #pragma unroll
        for(int j=0;j<4;++j){
            int row = qbase + qh*16 + lg*4 + j;
            #pragma unroll
            for(int t=0;t<4;++t)
                ctxb[(size_t)row*512 + h*64 + t*16 + l15] = f2b(acc[qh][t][j] * rl[j]);
        }
    }
}

// ---------------------------------------------------------------------------
extern "C" void kernel_launch(void* const* d_in, const int* in_sizes, int n_in,
                              void* d_out, int out_size, void* d_ws, size_t ws_size,
                              hipStream_t stream){
    (void)in_sizes; (void)n_in; (void)out_size; (void)ws_size;
    const float* query     = (const float*)d_in[0];
    const float* key_value = (const float*)d_in[1];
    const float* query_pos = (const float*)d_in[2];
    const float* key_pos   = (const float*)d_in[3];
    const int*   key_mask  = (const int*)d_in[4];
    const float* Wq  = (const float*)d_in[5];
    const float* bq  = (const float*)d_in[6];
    const float* Wk  = (const float*)d_in[7];
    const float* bk  = (const float*)d_in[8];
    const float* Wv  = (const float*)d_in[9];
    const float* bv  = (const float*)d_in[10];
    const float* Wo  = (const float*)d_in[11];
    const float* bo  = (const float*)d_in[12];
    const float* Wqb = (const float*)d_in[13];
    const float* Wkb = (const float*)d_in[14];

    char* ws = (char*)d_ws;
    const size_t MB = 1048576;
    unsigned short* kp    = (unsigned short*)(ws);            // 32MB
    unsigned short* vpT   = (unsigned short*)(ws + 32*MB);    // 32MB
    unsigned short* qp    = (unsigned short*)(ws + 64*MB);    //  8MB
    unsigned short* kvb   = (unsigned short*)(ws + 72*MB);    // 16MB chunk buf
    unsigned short* ctxb  = (unsigned short*)(ws + 72*MB);    //  8MB (after kvb dies)
    unsigned short* WtQ   = (unsigned short*)(ws + 88*MB);    // 4 x 0.5MB
    unsigned short* WtK   = WtQ + 262144;
    unsigned short* WtV   = WtK + 262144;
    unsigned short* WtO   = WtV + 262144;
    float*          qwg   = (float*)(ws + 90*MB);             // 16KB
    float*          kfg   = (float*)(ws + 90*MB + 65536);     // 64KB
    unsigned short* qb    = (unsigned short*)d_out;           // dead before O-proj

    wt4_kernel<<<dim3(8,8,4), 256, 0, stream>>>(Wq, Wk, Wv, Wo, WtQ);
    posfeat_kernel<<<20, 256, 0, stream>>>(query_pos, key_pos, Wqb, Wkb, key_mask, qwg, kfg);

    // Q path: convert + project
    cvt_kernel<<<2048, 256, 0, stream>>>(query, qb, 524288);           // 4M elems
    gemm512g<0><<<256, 256, 0, stream>>>(qb, WtQ, bq, qp);

    // K/V path, 2 chunks of 16384 rows each
    for(int c=0; c<2; ++c){
        const float* kvc = key_value + (size_t)c*16384*512;
        cvt_kernel<<<2048, 256, 0, stream>>>(kvc, kvb, 1048576);       // 8M elems
        gemm512g<0><<<512, 256, 0, stream>>>(kvb, WtK, bk, kp + (size_t)c*16384*512);
        gemm512g<2><<<512, 256, 0, stream>>>(kvb, WtV, bv, vpT + (size_t)c*8388608);
    }

    attn6_kernel<<<1024, 256, 0, stream>>>(qp, kp, vpT, qwg, kfg, ctxb);

    gemm512g<1><<<256, 256, 0, stream>>>(ctxb, WtO, bo, d_out);
}

// Round 9
// 184.760 us; speedup vs baseline: 2.0167x; 2.0167x over previous
//
#include <hip/hip_runtime.h>
#include <hip/hip_bf16.h>
#include <stdint.h>

// Shapes (fixed): B=4, N=8, Q=256, K=1024, D_MODEL=512, H=8, Dh=64, R=8, sigma=0.05

typedef __attribute__((ext_vector_type(8))) short bf16x8;
typedef __attribute__((ext_vector_type(4))) float f32x4;
typedef __attribute__((ext_vector_type(2))) float f32x2;

__device__ __forceinline__ unsigned short f2b(float f){
    unsigned int u = __builtin_bit_cast(unsigned int, f);
    unsigned int r = u + 0x7fffu + ((u >> 16) & 1u);   // RNE
    return (unsigned short)(r >> 16);
}

// packed f32->bf16x2 (RNE), single HW instr
__device__ __forceinline__ unsigned cvtpk2(float lo, float hi){
    unsigned r;
    asm("v_cvt_pk_bf16_f32 %0, %1, %2" : "=v"(r) : "v"(lo), "v"(hi));
    return r;
}

// single-level XOR swizzle for 64-col bf16 LDS tiles (0 conflicts measured r2)
__device__ __forceinline__ int swz(int row, int byteInRow){
    return row*128 + (byteInRow ^ ((row & 7) << 4));
}

// direct-to-LDS async copy, 16B per lane
#define GLDS16(g, l) __builtin_amdgcn_global_load_lds( \
    (const __attribute__((address_space(1))) void*)(g), \
    (__attribute__((address_space(3))) void*)(l), 16, 0, 0)

// DPP butterflies within 16-lane row
template<int CTRL>
__device__ __forceinline__ float dpp_mov(float x){
    return __builtin_bit_cast(float,
        __builtin_amdgcn_update_dpp(0, __builtin_bit_cast(int, x), CTRL, 0xF, 0xF, true));
}
__device__ __forceinline__ float grp16_max(float x){
    x = fmaxf(x, dpp_mov<0xB1>(x));
    x = fmaxf(x, dpp_mov<0x4E>(x));
    x = fmaxf(x, dpp_mov<0x141>(x));
    x = fmaxf(x, dpp_mov<0x140>(x));
    return x;
}
__device__ __forceinline__ float grp16_sum(float x){
    x += dpp_mov<0xB1>(x);
    x += dpp_mov<0x4E>(x);
    x += dpp_mov<0x141>(x);
    x += dpp_mov<0x140>(x);
    return x;
}

// ---------------- all 4 weight transposes in one launch ---------------------
__global__ __launch_bounds__(256) void wt4_kernel(
    const float* __restrict__ Wq, const float* __restrict__ Wk,
    const float* __restrict__ Wv, const float* __restrict__ Wo,
    unsigned short* __restrict__ WtBase){
    __shared__ float tile[64][65];
    int kt = blockIdx.x, nt = blockIdx.y, wsel = blockIdx.z;
    const float* W = (wsel == 0) ? Wq : (wsel == 1) ? Wk : (wsel == 2) ? Wv : Wo;
    unsigned short* Wt = WtBase + (size_t)wsel * 262144;
    int tid = threadIdx.x;
    #pragma unroll
    for(int it=0; it<16; ++it){
        int idx = it*256 + tid;
        int r = idx >> 6, c = idx & 63;
        tile[r][c] = W[(kt*64 + r)*512 + nt*64 + c];
    }
    __syncthreads();
    #pragma unroll
    for(int it=0; it<16; ++it){
        int idx = it*256 + tid;
        int r = idx >> 6, c = idx & 63;
        Wt[(nt*64 + r)*512 + kt*64 + c] = f2b(tile[c][r]);
    }
}

// ---------------- positional features (rank-3 collapsed bias) ---------------
__global__ __launch_bounds__(256) void posfeat_kernel(
    const float* __restrict__ qpos, const float* __restrict__ kpos,
    const float* __restrict__ Wqb,  const float* __restrict__ Wkb,
    const int* __restrict__ mask,
    float* __restrict__ qwg,        // [1024][4]
    float* __restrict__ kfg){       // [4096][4]
    const float L2E = 1.4426950408889634f;
    const float S8  = 0.35355339059327373f;
    int id = blockIdx.x*256 + threadIdx.x;
    if(id < 1024){
        const float* p = qpos + id*3;
        float x = p[0], y = p[1], z = p[2];
        float qw0 = 400.f*x, qw1 = 400.f*y, qw2 = 400.f*z;
        #pragma unroll
        for(int r=0;r<8;++r){
            float qb = x*Wqb[r] + y*Wqb[8+r] + z*Wqb[16+r];
            float c  = S8*qb;
            qw0 += c*Wkb[r];
            qw1 += c*Wkb[8+r];
            qw2 += c*Wkb[16+r];
        }
        float4 o = {L2E*qw0, L2E*qw1, L2E*qw2, 0.f};
        *reinterpret_cast<float4*>(qwg + (size_t)id*4) = o;
    } else if(id < 5120){
        int k = id - 1024;
        const float* p = kpos + k*3;
        float x = p[0], y = p[1], z = p[2];
        float n2 = -200.0f*(x*x + y*y + z*z)*L2E;
        int mk = mask[k];
        float4 o = {x, y, z, mk ? n2 : -3.0e38f};
        *reinterpret_cast<float4*>(kfg + (size_t)k*4) = o;
    }
}

// ---------------- f32 -> bf16 streaming convert (8 elems/thread) ------------
__global__ __launch_bounds__(256) void cvt_kernel(
    const float* __restrict__ in, unsigned short* __restrict__ out, int n8){
    for(int id = blockIdx.x*256 + threadIdx.x; id < n8; id += gridDim.x*256){
        const float4* ip = reinterpret_cast<const float4*>(in) + (size_t)id*2;
        float4 a = ip[0], b = ip[1];
        uint4 w;
        w.x = cvtpk2(a.x, a.y); w.y = cvtpk2(a.z, a.w);
        w.z = cvtpk2(b.x, b.y); w.w = cvtpk2(b.z, b.w);
        reinterpret_cast<uint4*>(out)[id] = w;
    }
}

// ---------------- GEMM (m97 structure): A bf16 [M][512] @ Bt bf16 -----------
// EPI: 0 = bf16 row-major, 1 = f32 row-major.
template<int EPI>
__global__ __launch_bounds__(256, 4) void gemm512g(
    const unsigned short* __restrict__ A,
    const unsigned short* __restrict__ Bt,
    const float* __restrict__ bias,
    void* __restrict__ Cv){
    __shared__ alignas(16) char sm[32768];
    char* As = sm;
    char* Bs = sm + 16384;

    int nwg = gridDim.x;
    int q8  = nwg >> 3;
    int bid = blockIdx.x;
    int wgid = (bid & 7)*q8 + (bid >> 3);    // XCD-chunked bijection
    int n0 = (wgid & 3)*128, m0 = (wgid >> 2)*128;

    int tid = threadIdx.x;
    int l = tid & 63, wid = tid >> 6;
    int wr = wid >> 1, wc = wid & 1;
    int l15 = l & 15, lg = l >> 4;

    int srow8 = l >> 3;
    int scolb = ((l & 7) ^ srow8) << 4;

    f32x4 acc[4][4];
    const f32x4 z4 = {0.f,0.f,0.f,0.f};
    #pragma unroll
    for(int m=0;m<4;++m)
        #pragma unroll
        for(int n=0;n<4;++n) acc[m][n] = z4;

    for(int kt=0; kt<8; ++kt){
        int k0 = kt*64;
        __syncthreads();
        #pragma unroll
        for(int i=0;i<4;++i){
            int row = wid*32 + i*8 + srow8;
            const char* asrc = (const char*)(A  + (size_t)(m0+row)*512 + k0) + scolb;
            const char* bsrc = (const char*)(Bt + (size_t)(n0+row)*512 + k0) + scolb;
            GLDS16(asrc, As + wid*4096 + i*1024);
            GLDS16(bsrc, Bs + wid*4096 + i*1024);
        }
        __syncthreads();
        #pragma unroll
        for(int kk=0; kk<2; ++kk){
            bf16x8 af[4], bfr[4];
            #pragma unroll
            for(int m=0;m<4;++m)
                af[m] = *reinterpret_cast<const bf16x8*>(As + swz(wr*64 + m*16 + l15, kk*64 + lg*16));
            #pragma unroll
            for(int n=0;n<4;++n)
                bfr[n] = *reinterpret_cast<const bf16x8*>(Bs + swz(wc*64 + n*16 + l15, kk*64 + lg*16));
            #pragma unroll
            for(int m=0;m<4;++m)
                #pragma unroll
                for(int n=0;n<4;++n)
                    acc[m][n] = __builtin_amdgcn_mfma_f32_16x16x32_bf16(af[m], bfr[n], acc[m][n], 0, 0, 0);
        }
    }

    #pragma unroll
    for(int m=0;m<4;++m){
        int row = m0 + wr*64 + m*16 + lg*4;
        #pragma unroll
        for(int n=0;n<4;++n){
            int col = n0 + wc*64 + n*16 + l15;
            float bv = bias[col];
            #pragma unroll
            for(int j=0;j<4;++j){
                float val = acc[m][n][j] + bv;
                if(EPI == 0)
                    reinterpret_cast<unsigned short*>(Cv)[(size_t)(row+j)*512 + col] = f2b(val);
                else
                    reinterpret_cast<float*>(Cv)[(size_t)(row+j)*512 + col] = val;
            }
        }
    }
}

// ---------------- merged K|V projection: Bt = [WtK; WtV] (N=1024) -----------
// n0<512 -> K row-major bf16; n0>=512 -> V transposed per-head into vpT.
__global__ __launch_bounds__(256, 4) void gemm_kv2(
    const unsigned short* __restrict__ A,      // [16384][512] bf16 (chunk)
    const unsigned short* __restrict__ BtKV,   // [1024][512] bf16
    const float* __restrict__ bk_, const float* __restrict__ bv_,
    unsigned short* __restrict__ kp,           // chunk base
    unsigned short* __restrict__ vpT){         // chunk base
    __shared__ alignas(16) char sm[32768];
    char* As = sm;
    char* Bs = sm + 16384;

    int nwg = gridDim.x;                     // 1024
    int q8  = nwg >> 3;
    int bid = blockIdx.x;
    int wgid = (bid & 7)*q8 + (bid >> 3);
    int n0 = (wgid & 7)*128, m0 = (wgid >> 3)*128;

    int tid = threadIdx.x;
    int l = tid & 63, wid = tid >> 6;
    int wr = wid >> 1, wc = wid & 1;
    int l15 = l & 15, lg = l >> 4;

    int srow8 = l >> 3;
    int scolb = ((l & 7) ^ srow8) << 4;

    f32x4 acc[4][4];
    const f32x4 z4 = {0.f,0.f,0.f,0.f};
    #pragma unroll
    for(int m=0;m<4;++m)
        #pragma unroll
        for(int n=0;n<4;++n) acc[m][n] = z4;

    for(int kt=0; kt<8; ++kt){
        int k0 = kt*64;
        __syncthreads();
        #pragma unroll
        for(int i=0;i<4;++i){
            int row = wid*32 + i*8 + srow8;
            const char* asrc = (const char*)(A    + (size_t)(m0+row)*512 + k0) + scolb;
            const char* bsrc = (const char*)(BtKV + (size_t)(n0+row)*512 + k0) + scolb;
            GLDS16(asrc, As + wid*4096 + i*1024);
            GLDS16(bsrc, Bs + wid*4096 + i*1024);
        }
        __syncthreads();
        #pragma unroll
        for(int kk=0; kk<2; ++kk){
            bf16x8 af[4], bfr[4];
            #pragma unroll
            for(int m=0;m<4;++m)
                af[m] = *reinterpret_cast<const bf16x8*>(As + swz(wr*64 + m*16 + l15, kk*64 + lg*16));
            #pragma unroll
            for(int n=0;n<4;++n)
                bfr[n] = *reinterpret_cast<const bf16x8*>(Bs + swz(wc*64 + n*16 + l15, kk*64 + lg*16));
            #pragma unroll
            for(int m=0;m<4;++m)
                #pragma unroll
                for(int n=0;n<4;++n)
                    acc[m][n] = __builtin_amdgcn_mfma_f32_16x16x32_bf16(af[m], bfr[n], acc[m][n], 0, 0, 0);
        }
    }

    if(n0 < 512){
        #pragma unroll
        for(int m=0;m<4;++m){
            int row = m0 + wr*64 + m*16 + lg*4;
            #pragma unroll
            for(int n=0;n<4;++n){
                int col = n0 + wc*64 + n*16 + l15;
                float bv = bk_[col];
                #pragma unroll
                for(int j=0;j<4;++j)
                    kp[(size_t)(row+j)*512 + col] = f2b(acc[m][n][j] + bv);
            }
        }
    } else {
        int z = m0 >> 10;                    // chunk-local z (0..15)
        #pragma unroll
        for(int m=0;m<4;++m){
            int kloc = (m0 & 1023) + wr*64 + m*16 + lg*4;
            #pragma unroll
            for(int n=0;n<4;++n){
                int col = n0 - 512 + wc*64 + n*16 + l15;   // h*64+d
                float bv = bv_[col];
                int vrow = (z*8 + (col >> 6))*64 + (col & 63);
                uint2 w;
                w.x = cvtpk2(acc[m][n][0] + bv, acc[m][n][1] + bv);
                w.y = cvtpk2(acc[m][n][2] + bv, acc[m][n][3] + bv);
                *reinterpret_cast<uint2*>(vpT + (size_t)vrow*1024 + kloc) = w;
            }
        }
    }
}

// ---------------- attention v7: attn4 + 1-deep K/bias register prefetch -----
// 512 blocks x 4 waves; wave = 32 q-rows; block = (z,h,q-half). Barrier-free.
__global__ __launch_bounds__(256) void attn7_kernel(
    const unsigned short* __restrict__ qp,   // [8192][512] bf16
    const unsigned short* __restrict__ kp,   // [32768][512] bf16
    const unsigned short* __restrict__ vpT,  // [(z*8+h)*64+d][1024] bf16
    const float* __restrict__ qwg,           // [1024][4] L2E-folded
    const float* __restrict__ kfg,           // [4096][4] L2E-folded
    unsigned short* __restrict__ ctxb){      // [8192][512] bf16
    __shared__ alignas(16) char Ps[16384];   // 4 waves x 4096B: [32 q][64 k] swz

    const float SCALE2 = 0.18033688011112042f;   // 0.125 * log2(e)
    const float THR = 10.0f;

    int bid = blockIdx.x;
    int xcd = bid & 7, idx = bid >> 3;
    int zh = xcd*32 + (idx >> 1), qs = idx & 1;
    int z = zh >> 3, h = zh & 7;
    int b = z >> 3;
    int tid = threadIdx.x, l = tid & 63, wid = tid >> 6;
    int l15 = l & 15, lg = l >> 4;

    const unsigned short* kbase = kp  + (size_t)(z*1024)*512 + h*64;
    const unsigned short* vbase = vpT + (size_t)((z*8+h)*64)*1024;
    const float* kfb = kfg + (size_t)(b*1024)*4;
    char* Pw = Ps + wid*4096;
    int qbase = z*256 + qs*128 + wid*32;

    bf16x8 qf[2][2];
    #pragma unroll
    for(int qh=0;qh<2;++qh)
        #pragma unroll
        for(int kk=0;kk<2;++kk)
            qf[qh][kk] = *reinterpret_cast<const bf16x8*>(
                qp + (size_t)(qbase + qh*16 + l15)*512 + h*64 + kk*32 + lg*8);

    f32x2 qwp[2][2][3];
    #pragma unroll
    for(int qh=0;qh<2;++qh){
        f32x4 qv[4];
        #pragma unroll
        for(int j=0;j<4;++j)
            qv[j] = *reinterpret_cast<const f32x4*>(
                qwg + (size_t)(b*256 + qs*128 + wid*32 + qh*16 + lg*4 + j)*4);
        #pragma unroll
        for(int p=0;p<2;++p)
            #pragma unroll
            for(int f=0;f<3;++f)
                qwp[qh][p][f] = (f32x2){qv[2*p][f], qv[2*p+1][f]};
    }

    float mrun[2][4];
    f32x4 psum[2];
    f32x4 acc[2][4];
    const f32x4 z4 = {0.f,0.f,0.f,0.f};
    #pragma unroll
    for(int qh=0;qh<2;++qh){
        #pragma unroll
        for(int j=0;j<4;++j) mrun[qh][j] = -3.0e38f;
        psum[qh] = z4;
        #pragma unroll
        for(int t=0;t<4;++t) acc[qh][t] = z4;
    }

    // K-tile register load (static indices after inline)
    auto loadk = [&](int kt, bf16x8 (&kf)[4][2], f32x4 (&kv)[4]){
        const unsigned short* ktk = kbase + (size_t)(kt*64)*512;
        #pragma unroll
        for(int t=0;t<4;++t){
            #pragma unroll
            for(int kk=0;kk<2;++kk)
                kf[t][kk] = *reinterpret_cast<const bf16x8*>(
                    ktk + (size_t)(t*16 + l15)*512 + kk*32 + lg*8);
            kv[t] = *reinterpret_cast<const f32x4*>(kfb + (size_t)(kt*64 + t*16 + l15)*4);
        }
    };

    auto body = [&](int kt, bf16x8 (&kf)[4][2], f32x4 (&kv)[4]){
        f32x4 s[2][4];
        #pragma unroll
        for(int qh=0;qh<2;++qh)
            #pragma unroll
            for(int t=0;t<4;++t) s[qh][t] = z4;
        __builtin_amdgcn_s_setprio(1);
        #pragma unroll
        for(int t=0;t<4;++t)
            #pragma unroll
            for(int kk=0;kk<2;++kk)
                #pragma unroll
                for(int qh=0;qh<2;++qh)
                    s[qh][t] = __builtin_amdgcn_mfma_f32_16x16x32_bf16(qf[qh][kk], kf[t][kk], s[qh][t], 0, 0, 0);
        __builtin_amdgcn_s_setprio(0);

        // V fragments issued early so their latency hides under softmax VALU
        bf16x8 vf[4][2];
        #pragma unroll
        for(int t=0;t<4;++t)
            #pragma unroll
            for(int kk=0;kk<2;++kk)
                vf[t][kk] = *reinterpret_cast<const bf16x8*>(
                    vbase + (size_t)(t*16 + l15)*1024 + kt*64 + kk*32 + lg*8);

        #pragma unroll
        for(int t=0;t<4;++t){
            f32x2 c0 = {kv[t][0],kv[t][0]}, c1 = {kv[t][1],kv[t][1]},
                  c2 = {kv[t][2],kv[t][2]}, c3 = {kv[t][3],kv[t][3]};
            #pragma unroll
            for(int qh=0;qh<2;++qh){
                f32x2 b01 = qwp[qh][0][0]*c0 + qwp[qh][0][1]*c1 + qwp[qh][0][2]*c2 + c3;
                f32x2 b23 = qwp[qh][1][0]*c0 + qwp[qh][1][1]*c1 + qwp[qh][1][2]*c2 + c3;
                f32x2 s01 = {s[qh][t][0], s[qh][t][1]};
                f32x2 s23 = {s[qh][t][2], s[qh][t][3]};
                s01 = s01*SCALE2 + b01;
                s23 = s23*SCALE2 + b23;
                s[qh][t][0] = s01.x; s[qh][t][1] = s01.y;
                s[qh][t][2] = s23.x; s[qh][t][3] = s23.y;
            }
        }
        float pm[2][4];
        bool need = false;
        #pragma unroll
        for(int qh=0;qh<2;++qh)
            #pragma unroll
            for(int j=0;j<4;++j){
                float mx = fmaxf(fmaxf(s[qh][0][j], s[qh][1][j]), fmaxf(s[qh][2][j], s[qh][3][j]));
                mx = grp16_max(mx);
                pm[qh][j] = mx;
                need = need || (mx > mrun[qh][j] + THR);
            }
        if(__any(need ? 1 : 0)){
            #pragma unroll
            for(int qh=0;qh<2;++qh)
                #pragma unroll
                for(int j=0;j<4;++j){
                    float mn = fmaxf(mrun[qh][j], pm[qh][j]);
                    float scl = exp2f(mrun[qh][j] - mn);
                    mrun[qh][j] = mn;
                    psum[qh][j] *= scl;
                    #pragma unroll
                    for(int t=0;t<4;++t) acc[qh][t][j] *= scl;
                }
        }
        #pragma unroll
        for(int qh=0;qh<2;++qh){
            int row0 = qh*16 + lg*4;
            #pragma unroll
            for(int t=0;t<4;++t){
                float p0 = exp2f(s[qh][t][0] - mrun[qh][0]);
                float p1 = exp2f(s[qh][t][1] - mrun[qh][1]);
                float p2 = exp2f(s[qh][t][2] - mrun[qh][2]);
                float p3 = exp2f(s[qh][t][3] - mrun[qh][3]);
                psum[qh] += (f32x4){p0, p1, p2, p3};
                unsigned w01 = cvtpk2(p0, p1);
                unsigned w23 = cvtpk2(p2, p3);
                int cb = (t*16 + l15)*2;
                *reinterpret_cast<unsigned short*>(Pw + swz(row0+0, cb)) = (unsigned short)w01;
                *reinterpret_cast<unsigned short*>(Pw + swz(row0+1, cb)) = (unsigned short)(w01 >> 16);
                *reinterpret_cast<unsigned short*>(Pw + swz(row0+2, cb)) = (unsigned short)w23;
                *reinterpret_cast<unsigned short*>(Pw + swz(row0+3, cb)) = (unsigned short)(w23 >> 16);
            }
        }
        __builtin_amdgcn_s_setprio(1);
        #pragma unroll
        for(int kk=0;kk<2;++kk){
            #pragma unroll
            for(int qh=0;qh<2;++qh){
                bf16x8 pa = *reinterpret_cast<const bf16x8*>(Pw + swz(qh*16 + l15, kk*64 + lg*16));
                #pragma unroll
                for(int t=0;t<4;++t)
                    acc[qh][t] = __builtin_amdgcn_mfma_f32_16x16x32_bf16(pa, vf[t][kk], acc[qh][t], 0, 0, 0);
            }
        }
        __builtin_amdgcn_s_setprio(0);
    };

    // software pipeline: prefetch next K tile before current body
    bf16x8 kfA[4][2], kfB[4][2];
    f32x4 kvA[4], kvB[4];
    loadk(0, kfA, kvA);
    #pragma unroll 1
    for(int kt=0; kt<16; kt+=2){
        loadk(kt+1, kfB, kvB);           // in flight across body A
        body(kt, kfA, kvA);
        if(kt < 14) loadk(kt+2, kfA, kvA);
        body(kt+1, kfB, kvB);
    }

    #pragma unroll
    for(int qh=0;qh<2;++qh){
        float rl[4];
        #pragma unroll
        for(int j=0;j<4;++j) rl[j] = 1.0f / grp16_sum(psum[qh][j]);
        #pragma unroll
        for(int j=0;j<4;++j){
            int row = qbase + qh*16 + lg*4 + j;
            #pragma unroll
            for(int t=0;t<4;++t)
                ctxb[(size_t)row*512 + h*64 + t*16 + l15] = f2b(acc[qh][t][j] * rl[j]);
        }
    }
}

// ---------------------------------------------------------------------------
extern "C" void kernel_launch(void* const* d_in, const int* in_sizes, int n_in,
                              void* d_out, int out_size, void* d_ws, size_t ws_size,
                              hipStream_t stream){
    (void)in_sizes; (void)n_in; (void)out_size; (void)ws_size;
    const float* query     = (const float*)d_in[0];
    const float* key_value = (const float*)d_in[1];
    const float* query_pos = (const float*)d_in[2];
    const float* key_pos   = (const float*)d_in[3];
    const int*   key_mask  = (const int*)d_in[4];
    const float* Wq  = (const float*)d_in[5];
    const float* bq  = (const float*)d_in[6];
    const float* Wk  = (const float*)d_in[7];
    const float* bk  = (const float*)d_in[8];
    const float* Wv  = (const float*)d_in[9];
    const float* bv  = (const float*)d_in[10];
    const float* Wo  = (const float*)d_in[11];
    const float* bo  = (const float*)d_in[12];
    const float* Wqb = (const float*)d_in[13];
    const float* Wkb = (const float*)d_in[14];

    char* ws = (char*)d_ws;
    const size_t MB = 1048576;
    unsigned short* kp    = (unsigned short*)(ws);            // 32MB
    unsigned short* vpT   = (unsigned short*)(ws + 32*MB);    // 32MB
    unsigned short* qp    = (unsigned short*)(ws + 64*MB);    //  8MB
    unsigned short* kvb   = (unsigned short*)(ws + 72*MB);    // 16MB chunk buf
    unsigned short* ctxb  = (unsigned short*)(ws + 72*MB);    //  8MB (after kvb dies)
    unsigned short* WtQ   = (unsigned short*)(ws + 88*MB);    // Q | K | V | O
    unsigned short* WtK   = WtQ + 262144;                     // K,V contiguous!
    unsigned short* WtO   = WtQ + 3*262144;
    float*          qwg   = (float*)(ws + 90*MB);             // 16KB
    float*          kfg   = (float*)(ws + 90*MB + 65536);     // 64KB
    unsigned short* qb    = (unsigned short*)d_out;           // dead before O-proj

    wt4_kernel<<<dim3(8,8,4), 256, 0, stream>>>(Wq, Wk, Wv, Wo, WtQ);
    posfeat_kernel<<<20, 256, 0, stream>>>(query_pos, key_pos, Wqb, Wkb, key_mask, qwg, kfg);

    // Q path: convert + project
    cvt_kernel<<<2048, 256, 0, stream>>>(query, qb, 524288);
    gemm512g<0><<<256, 256, 0, stream>>>(qb, WtQ, bq, qp);

    // K/V path, 2 chunks of 16384 rows; one merged K|V GEMM per chunk
    for(int c=0; c<2; ++c){
        const float* kvc = key_value + (size_t)c*16384*512;
        cvt_kernel<<<2048, 256, 0, stream>>>(kvc, kvb, 1048576);
        gemm_kv2<<<1024, 256, 0, stream>>>(kvb, WtK, bk, bv,
                                           kp + (size_t)c*16384*512,
                                           vpT + (size_t)c*8388608);
    }

    attn7_kernel<<<512, 256, 0, stream>>>(qp, kp, vpT, qwg, kfg, ctxb);

    gemm512g<1><<<256, 256, 0, stream>>>(ctxb, WtO, bo, d_out);
}